// Round 7
// baseline (275.481 us; speedup 1.0000x reference)
//
#include <hip/hip_runtime.h>
#include <hip/hip_bf16.h>
#include <math.h>

// Problem constants
#define BB 4
#define TT 2048
#define CC 1024
#define HH 16
#define HD 64
#define C3 3072
#define MM (BB * TT)   // 8192

typedef __attribute__((ext_vector_type(8))) short bf16x8;  // MFMA A/B frag (4 VGPRs)
typedef __attribute__((ext_vector_type(4))) float f32x4;   // MFMA C/D frag
typedef __attribute__((ext_vector_type(4))) short s16x4;

__device__ inline short f32_to_bf16_bits(float f) {
    unsigned u = __float_as_uint(f);
    u += 0x7fffu + ((u >> 16) & 1u);   // round-to-nearest-even
    return (short)(u >> 16);
}

__device__ inline void async_copy16(const void* g, void* l) {
    __builtin_amdgcn_global_load_lds((const __attribute__((address_space(1))) void*)g,
                                     (__attribute__((address_space(3))) void*)l, 16, 0, 0);
}

// ---------------- cast x: fp32 -> bf16, flat, 8 elems/thread
__global__ __launch_bounds__(256) void cast_x(const float* __restrict__ in,
                                              short* __restrict__ out) {
    int i = (blockIdx.x * 256 + threadIdx.x) * 8;
    float4 a = *(const float4*)(in + i);
    float4 b = *(const float4*)(in + i + 4);
    bf16x8 o;
    o[0] = f32_to_bf16_bits(a.x); o[1] = f32_to_bf16_bits(a.y);
    o[2] = f32_to_bf16_bits(a.z); o[3] = f32_to_bf16_bits(a.w);
    o[4] = f32_to_bf16_bits(b.x); o[5] = f32_to_bf16_bits(b.y);
    o[6] = f32_to_bf16_bits(b.z); o[7] = f32_to_bf16_bits(b.w);
    *(bf16x8*)(out + i) = o;
}

// ---------------- transpose-cast: w[K][N] fp32 -> wt[N][K] bf16, 64x64 tiles
__global__ __launch_bounds__(256) void tcast(const float* __restrict__ w,
                                             short* __restrict__ wt,
                                             int K, int N) {
    __shared__ short tile[64][68];
    const int n0 = blockIdx.x * 64, k0 = blockIdx.y * 64;
    const int tid = threadIdx.x;
#pragma unroll
    for (int it = 0; it < 4; ++it) {
        int idx = it * 1024 + tid * 4;
        int r = idx >> 6, c = idx & 63;
        float4 v = *(const float4*)&w[(size_t)(k0 + r) * N + n0 + c];
        tile[r][c + 0] = f32_to_bf16_bits(v.x);
        tile[r][c + 1] = f32_to_bf16_bits(v.y);
        tile[r][c + 2] = f32_to_bf16_bits(v.z);
        tile[r][c + 3] = f32_to_bf16_bits(v.w);
    }
    __syncthreads();
#pragma unroll
    for (int it = 0; it < 4; ++it) {
        int idx = it * 256 + tid;
        int rr = idx >> 4, kc = (idx & 15) * 4;
        s16x4 o = { tile[kc + 0][rr], tile[kc + 1][rr], tile[kc + 2][rr], tile[kc + 3][rr] };
        *(s16x4*)&wt[(size_t)(n0 + rr) * K + k0 + kc] = o;
    }
}

// ---------------- bf16 MFMA GEMM v2: 128x128 tile, BK=64, xor-swizzled LDS
template <bool QKV>
__global__ __launch_bounds__(256) void gemm128(const short* __restrict__ A,
                                               const short* __restrict__ Bt,
                                               const float* __restrict__ bias,
                                               short* __restrict__ qb,
                                               short* __restrict__ kb,
                                               short* __restrict__ vt,
                                               float* __restrict__ out,
                                               int N, int Kdim) {
    __shared__ __align__(16) short As[128 * 64];
    __shared__ __align__(16) short Bs[128 * 64];
    const int tid = threadIdx.x;
    const int wave = tid >> 6, lane = tid & 63;
    const int quad = lane >> 4, l16 = lane & 15;
    const int wm = wave >> 1, wn = wave & 1;
    const int m0 = blockIdx.y * 128, n0 = blockIdx.x * 128;

    f32x4 acc[4][4] = {};

    for (int k0 = 0; k0 < Kdim; k0 += 64) {
#pragma unroll
        for (int c2 = 0; c2 < 4; ++c2) {
            int g = (wave * 4 + c2) * 64 + lane;
            int row = g >> 3;
            int seg = (g & 7) ^ (row & 7);
            async_copy16(A + (size_t)(m0 + row) * Kdim + k0 + seg * 8, As + g * 8);
            async_copy16(Bt + (size_t)(n0 + row) * Kdim + k0 + seg * 8, Bs + g * 8);
        }
        __syncthreads();
#pragma unroll
        for (int ks = 0; ks < 2; ++ks) {
            bf16x8 af[4], bfv[4];
#pragma unroll
            for (int i = 0; i < 4; ++i) {
                int row = wm * 64 + i * 16 + l16;
                int u = (ks * 4 + quad) ^ (row & 7);
                af[i] = *(const bf16x8*)&As[row * 64 + u * 8];
            }
#pragma unroll
            for (int j = 0; j < 4; ++j) {
                int row = wn * 64 + j * 16 + l16;
                int u = (ks * 4 + quad) ^ (row & 7);
                bfv[j] = *(const bf16x8*)&Bs[row * 64 + u * 8];
            }
#pragma unroll
            for (int i = 0; i < 4; ++i)
#pragma unroll
                for (int j = 0; j < 4; ++j)
                    acc[i][j] = __builtin_amdgcn_mfma_f32_16x16x32_bf16(af[i], bfv[j], acc[i][j], 0, 0, 0);
        }
        __syncthreads();
    }

#pragma unroll
    for (int i = 0; i < 4; ++i)
#pragma unroll
        for (int j = 0; j < 4; ++j) {
            int n = n0 + wn * 64 + j * 16 + l16;
            float bv = bias[n];
            if (QKV) {
                int which = n >> 10, cc = n & 1023;
                int h = cc >> 6, d = cc & 63;
                if (which == 2) {
                    int m_base = m0 + wm * 64 + i * 16 + quad * 4;
                    int bb = m_base >> 11, t0 = m_base & 2047;
                    unsigned p0 = ((unsigned)(unsigned short)f32_to_bf16_bits(acc[i][j][0] + bv)) |
                                  ((unsigned)(unsigned short)f32_to_bf16_bits(acc[i][j][1] + bv) << 16);
                    unsigned p1 = ((unsigned)(unsigned short)f32_to_bf16_bits(acc[i][j][2] + bv)) |
                                  ((unsigned)(unsigned short)f32_to_bf16_bits(acc[i][j][3] + bv) << 16);
                    uint2 pk = {p0, p1};
                    *(uint2*)(vt + (((size_t)bb * HH + h) * HD + d) * TT + t0) = pk;
                } else {
#pragma unroll
                    for (int r = 0; r < 4; ++r) {
                        int m = m0 + wm * 64 + i * 16 + quad * 4 + r;
                        int bb = m >> 11, t = m & 2047;
                        short val = f32_to_bf16_bits((acc[i][j][r] + bv) * (which == 0 ? 0.125f : 1.0f));
                        size_t off = (((size_t)bb * HH + h) * TT + t) * HD + d;
                        if (which == 0) qb[off] = val;
                        else kb[off] = val;
                    }
                }
            } else {
#pragma unroll
                for (int r = 0; r < 4; ++r) {
                    int m = m0 + wm * 64 + i * 16 + quad * 4 + r;
                    out[(size_t)m * N + n] = acc[i][j][r] + bv;
                }
            }
        }
}

// ---------------- Flash attention v4: fold pair split ACROSS waves (waves 0-3 = hi
// 64-row tile, waves 4-7 = lo tile). Grid 16x64 -> 3 blocks/CU (LDS-limited), one
// unit per wave per j-tile. LDS K/V dbuf staging + fixed-max softmax as before.
__global__ __launch_bounds__(512, 6) void flash_attn(const short* __restrict__ qb,
                                                     const short* __restrict__ kb,
                                                     const short* __restrict__ vt,
                                                     short* __restrict__ ab) {
    __shared__ __align__(16) short Ksh[2][4096];
    __shared__ __align__(16) short Vsh[2][4096];
    __shared__ __align__(16) short plds[8][16][72];

    const int tid = threadIdx.x;
    const int wave = tid >> 6;       // 0..7
    const int lane = tid & 63;
    const int quad = lane >> 4;
    const int l16 = lane & 15;

    const int bh = blockIdx.y;
    const int i = blockIdx.x;        // 0..15 fold index
    const int njt = 32 - i;          // hi tile (31-i) needs tiles 0..31-i
    const bool is_hi = wave < 4;
    const int w4 = wave & 3;
    const int q_me = (is_hi ? (31 - i) : i) * 64 + w4 * 16;

    const short* qball = qb + (size_t)bh * TT * HD;
    const short* kball = kb + (size_t)bh * TT * HD;
    const short* vtall = vt + (size_t)bh * HD * TT;

    const int sidx = wave * 64 + lane;
    const int srow = sidx >> 3;
    const int sseg = (sidx & 7) ^ (srow & 7);
    const short* kgsrc = kball + (size_t)srow * HD + sseg * 8;
    const short* vgsrc = vtall + (size_t)srow * TT + sseg * 8;

    bf16x8 qf[2];
#pragma unroll
    for (int h = 0; h < 2; ++h)
        qf[h] = *(const bf16x8*)(qball + (size_t)(q_me + l16) * HD + h * 32 + quad * 8);

    f32x4 o[4] = {};
    float ls[4] = {0.f, 0.f, 0.f, 0.f};

    async_copy16(kgsrc, &Ksh[0][wave * 512]);
    async_copy16(vgsrc, &Vsh[0][wave * 512]);
    __syncthreads();

    for (int jt = 0; jt < njt; ++jt) {
        const int buf = jt & 1;
        if (jt + 1 < njt) {
            async_copy16(kgsrc + (size_t)(jt + 1) * 64 * HD, &Ksh[buf ^ 1][wave * 512]);
            async_copy16(vgsrc + (jt + 1) * 64, &Vsh[buf ^ 1][wave * 512]);
        }
        const int j0 = jt * 64;

        if (j0 <= q_me + 15) {
            f32x4 s[4];
#pragma unroll
            for (int cb = 0; cb < 4; ++cb) {
                int row = cb * 16 + l16;
                bf16x8 k0 = *(const bf16x8*)&Ksh[buf][(row * 8 + (quad ^ (row & 7))) * 8];
                bf16x8 k1 = *(const bf16x8*)&Ksh[buf][(row * 8 + ((4 + quad) ^ (row & 7))) * 8];
                f32x4 a = {};
                a = __builtin_amdgcn_mfma_f32_16x16x32_bf16(qf[0], k0, a, 0, 0, 0);
                a = __builtin_amdgcn_mfma_f32_16x16x32_bf16(qf[1], k1, a, 0, 0, 0);
                s[cb] = a;
            }
            if (j0 + 64 > q_me) {
#pragma unroll
                for (int cb = 0; cb < 4; ++cb) {
                    int j = j0 + cb * 16 + l16;
#pragma unroll
                    for (int r = 0; r < 4; ++r)
                        if (j > q_me + quad * 4 + r) s[cb][r] = -1e30f;
                }
            }
#pragma unroll
            for (int cb = 0; cb < 4; ++cb)
#pragma unroll
                for (int r = 0; r < 4; ++r) {
                    float p = __expf(s[cb][r]);
                    ls[r] += p;
                    plds[wave][quad * 4 + r][cb * 16 + l16] = f32_to_bf16_bits(p);
                }
            bf16x8 pa0 = *(const bf16x8*)&plds[wave][l16][quad * 8];
            bf16x8 pa1 = *(const bf16x8*)&plds[wave][l16][32 + quad * 8];
#pragma unroll
            for (int db = 0; db < 4; ++db) {
                int row = db * 16 + l16;
                bf16x8 v0 = *(const bf16x8*)&Vsh[buf][(row * 8 + (quad ^ (row & 7))) * 8];
                bf16x8 v1 = *(const bf16x8*)&Vsh[buf][(row * 8 + ((4 + quad) ^ (row & 7))) * 8];
                o[db] = __builtin_amdgcn_mfma_f32_16x16x32_bf16(pa0, v0, o[db], 0, 0, 0);
                o[db] = __builtin_amdgcn_mfma_f32_16x16x32_bf16(pa1, v1, o[db], 0, 0, 0);
            }
        }
        __syncthreads();
    }

    // epilogue
    const int b = bh >> 4, hd0 = (bh & 15) * HD;
    float inv[4];
#pragma unroll
    for (int r = 0; r < 4; ++r) {
        float t = ls[r];
#pragma unroll
        for (int off = 1; off < 16; off <<= 1) t += __shfl_xor(t, off, 64);
        inv[r] = 1.0f / t;
    }
#pragma unroll
    for (int r = 0; r < 4; ++r) {
        int q = q_me + quad * 4 + r;
#pragma unroll
        for (int db = 0; db < 4; ++db)
            ab[((size_t)(b * TT + q)) * CC + hd0 + db * 16 + l16] =
                f32_to_bf16_bits(o[db][r] * inv[r]);
    }
}

extern "C" void kernel_launch(void* const* d_in, const int* in_sizes, int n_in,
                              void* d_out, int out_size, void* d_ws, size_t ws_size,
                              hipStream_t stream) {
    const float* x      = (const float*)d_in[0];
    const float* w_attn = (const float*)d_in[1];
    const float* b_attn = (const float*)d_in[2];
    const float* w_proj = (const float*)d_in[3];
    const float* b_proj = (const float*)d_in[4];
    float* out = (float*)d_out;

    const size_t per = (size_t)BB * HH * TT * HD;  // 8,388,608
    short* xb      = (short*)d_ws;
    short* wt_attn = xb + per;
    short* wt_proj = wt_attn + (size_t)C3 * CC;
    short* qb      = wt_proj + (size_t)CC * CC;
    short* kb      = qb + per;
    short* vt      = kb + per;                     // [B,H,hd,T]
    short* ab      = vt + per;                     // [B,T,C] bf16

    cast_x<<<dim3(MM * CC / (256 * 8)), 256, 0, stream>>>(x, xb);
    tcast<<<dim3(C3 / 64, CC / 64), 256, 0, stream>>>(w_attn, wt_attn, CC, C3);
    tcast<<<dim3(CC / 64, CC / 64), 256, 0, stream>>>(w_proj, wt_proj, CC, CC);

    gemm128<true><<<dim3(C3 / 128, MM / 128), 256, 0, stream>>>(
        xb, wt_attn, b_attn, qb, kb, vt, nullptr, C3, CC);

    flash_attn<<<dim3(16, BB * HH), 512, 0, stream>>>(qb, kb, vt, ab);

    gemm128<false><<<dim3(CC / 128, MM / 128), 256, 0, stream>>>(
        ab, wt_proj, b_proj, nullptr, nullptr, nullptr, out, CC, CC);
}

// Round 9
// 266.861 us; speedup vs baseline: 1.0323x; 1.0323x over previous
//
#include <hip/hip_runtime.h>
#include <hip/hip_bf16.h>
#include <math.h>

// Problem constants
#define BB 4
#define TT 2048
#define CC 1024
#define HH 16
#define HD 64
#define C3 3072
#define MM (BB * TT)   // 8192

typedef __attribute__((ext_vector_type(8))) short bf16x8;  // MFMA A/B frag (4 VGPRs)
typedef __attribute__((ext_vector_type(4))) float f32x4;   // MFMA C/D frag
typedef __attribute__((ext_vector_type(4))) short s16x4;

#define QSCALE 0.1803368801111244f  // 0.125 * log2(e): scores land in log2 domain

__device__ inline float fast_exp2(float x) { return __builtin_amdgcn_exp2f(x); }

__device__ inline short f32_to_bf16_bits(float f) {
    unsigned u = __float_as_uint(f);
    u += 0x7fffu + ((u >> 16) & 1u);   // round-to-nearest-even
    return (short)(u >> 16);
}

__device__ inline void async_copy16(const void* g, void* l) {
    __builtin_amdgcn_global_load_lds((const __attribute__((address_space(1))) void*)g,
                                     (__attribute__((address_space(3))) void*)l, 16, 0, 0);
}

// ---------------- cast x: fp32 -> bf16, flat, 8 elems/thread
__global__ __launch_bounds__(256) void cast_x(const float* __restrict__ in,
                                              short* __restrict__ out) {
    int i = (blockIdx.x * 256 + threadIdx.x) * 8;
    float4 a = *(const float4*)(in + i);
    float4 b = *(const float4*)(in + i + 4);
    bf16x8 o;
    o[0] = f32_to_bf16_bits(a.x); o[1] = f32_to_bf16_bits(a.y);
    o[2] = f32_to_bf16_bits(a.z); o[3] = f32_to_bf16_bits(a.w);
    o[4] = f32_to_bf16_bits(b.x); o[5] = f32_to_bf16_bits(b.y);
    o[6] = f32_to_bf16_bits(b.z); o[7] = f32_to_bf16_bits(b.w);
    *(bf16x8*)(out + i) = o;
}

// ---------------- transpose-cast: w[K][N] fp32 -> wt[N][K] bf16, 64x64 tiles
__global__ __launch_bounds__(256) void tcast(const float* __restrict__ w,
                                             short* __restrict__ wt,
                                             int K, int N) {
    __shared__ short tile[64][68];
    const int n0 = blockIdx.x * 64, k0 = blockIdx.y * 64;
    const int tid = threadIdx.x;
#pragma unroll
    for (int it = 0; it < 4; ++it) {
        int idx = it * 1024 + tid * 4;
        int r = idx >> 6, c = idx & 63;
        float4 v = *(const float4*)&w[(size_t)(k0 + r) * N + n0 + c];
        tile[r][c + 0] = f32_to_bf16_bits(v.x);
        tile[r][c + 1] = f32_to_bf16_bits(v.y);
        tile[r][c + 2] = f32_to_bf16_bits(v.z);
        tile[r][c + 3] = f32_to_bf16_bits(v.w);
    }
    __syncthreads();
#pragma unroll
    for (int it = 0; it < 4; ++it) {
        int idx = it * 256 + tid;
        int rr = idx >> 4, kc = (idx & 15) * 4;
        s16x4 o = { tile[kc + 0][rr], tile[kc + 1][rr], tile[kc + 2][rr], tile[kc + 3][rr] };
        *(s16x4*)&wt[(size_t)(n0 + rr) * K + k0 + kc] = o;
    }
}

// ---------------- bf16 MFMA GEMM v2: 128x128 tile, BK=64, xor-swizzled LDS
template <bool QKV>
__global__ __launch_bounds__(256) void gemm128(const short* __restrict__ A,
                                               const short* __restrict__ Bt,
                                               const float* __restrict__ bias,
                                               short* __restrict__ qb,
                                               short* __restrict__ kb,
                                               short* __restrict__ vt,
                                               float* __restrict__ out,
                                               int N, int Kdim) {
    __shared__ __align__(16) short As[128 * 64];
    __shared__ __align__(16) short Bs[128 * 64];
    const int tid = threadIdx.x;
    const int wave = tid >> 6, lane = tid & 63;
    const int quad = lane >> 4, l16 = lane & 15;
    const int wm = wave >> 1, wn = wave & 1;
    const int m0 = blockIdx.y * 128, n0 = blockIdx.x * 128;

    f32x4 acc[4][4] = {};

    for (int k0 = 0; k0 < Kdim; k0 += 64) {
#pragma unroll
        for (int c2 = 0; c2 < 4; ++c2) {
            int g = (wave * 4 + c2) * 64 + lane;
            int row = g >> 3;
            int seg = (g & 7) ^ (row & 7);
            async_copy16(A + (size_t)(m0 + row) * Kdim + k0 + seg * 8, As + g * 8);
            async_copy16(Bt + (size_t)(n0 + row) * Kdim + k0 + seg * 8, Bs + g * 8);
        }
        __syncthreads();
#pragma unroll
        for (int ks = 0; ks < 2; ++ks) {
            bf16x8 af[4], bfv[4];
#pragma unroll
            for (int i = 0; i < 4; ++i) {
                int row = wm * 64 + i * 16 + l16;
                int u = (ks * 4 + quad) ^ (row & 7);
                af[i] = *(const bf16x8*)&As[row * 64 + u * 8];
            }
#pragma unroll
            for (int j = 0; j < 4; ++j) {
                int row = wn * 64 + j * 16 + l16;
                int u = (ks * 4 + quad) ^ (row & 7);
                bfv[j] = *(const bf16x8*)&Bs[row * 64 + u * 8];
            }
#pragma unroll
            for (int i = 0; i < 4; ++i)
#pragma unroll
                for (int j = 0; j < 4; ++j)
                    acc[i][j] = __builtin_amdgcn_mfma_f32_16x16x32_bf16(af[i], bfv[j], acc[i][j], 0, 0, 0);
        }
        __syncthreads();
    }

#pragma unroll
    for (int i = 0; i < 4; ++i)
#pragma unroll
        for (int j = 0; j < 4; ++j) {
            int n = n0 + wn * 64 + j * 16 + l16;
            float bv = bias[n];
            if (QKV) {
                int which = n >> 10, cc = n & 1023;
                int h = cc >> 6, d = cc & 63;
                if (which == 2) {
                    int m_base = m0 + wm * 64 + i * 16 + quad * 4;
                    int bb = m_base >> 11, t0 = m_base & 2047;
                    unsigned p0 = ((unsigned)(unsigned short)f32_to_bf16_bits(acc[i][j][0] + bv)) |
                                  ((unsigned)(unsigned short)f32_to_bf16_bits(acc[i][j][1] + bv) << 16);
                    unsigned p1 = ((unsigned)(unsigned short)f32_to_bf16_bits(acc[i][j][2] + bv)) |
                                  ((unsigned)(unsigned short)f32_to_bf16_bits(acc[i][j][3] + bv) << 16);
                    uint2 pk = {p0, p1};
                    *(uint2*)(vt + (((size_t)bb * HH + h) * HD + d) * TT + t0) = pk;
                } else {
#pragma unroll
                    for (int r = 0; r < 4; ++r) {
                        int m = m0 + wm * 64 + i * 16 + quad * 4 + r;
                        int bb = m >> 11, t = m & 2047;
                        short val = f32_to_bf16_bits((acc[i][j][r] + bv) * (which == 0 ? QSCALE : 1.0f));
                        size_t off = (((size_t)bb * HH + h) * TT + t) * HD + d;
                        if (which == 0) qb[off] = val;
                        else kb[off] = val;
                    }
                }
            } else {
#pragma unroll
                for (int r = 0; r < 4; ++r) {
                    int m = m0 + wm * 64 + i * 16 + quad * 4 + r;
                    out[(size_t)m * N + n] = acc[i][j][r] + bv;
                }
            }
        }
}

// ---------------- Flash attention v5: v3 structure (512 thr, fold pair of 128-row
// supertiles per block, per-wave hi+lo units) + BJ=128 double-subtile iterations
// (half the barriers, 2x DMA burst, per-wave ILP) + exp2 softmax
// (q pre-scaled by 0.125*log2e; p = exp2(s), identical to exp(qk/8)).
__global__ __launch_bounds__(512, 4) void flash_attn(const short* __restrict__ qb,
                                                     const short* __restrict__ kb,
                                                     const short* __restrict__ vt,
                                                     short* __restrict__ ab) {
    __shared__ __align__(16) short Ksh[2][2][4096];  // [buf][subtile][64j x 64d swizzled]
    __shared__ __align__(16) short Vsh[2][2][4096];  // [buf][subtile][64d x 64j swizzled]
    __shared__ __align__(16) short plds[8][16][72];

    const int tid = threadIdx.x;
    const int wave = tid >> 6;
    const int lane = tid & 63;
    const int quad = lane >> 4;
    const int l16 = lane & 15;

    const int bh = blockIdx.y;
    const int i = blockIdx.x;        // 0..7 fold index
    const int nst = 16 - i;          // super-iterations (pairs of 64-j subtiles)
    const int q_lo = i * 128 + wave * 16;
    const int q_hi = (15 - i) * 128 + wave * 16;

    const short* qball = qb + (size_t)bh * TT * HD;
    const short* kball = kb + (size_t)bh * TT * HD;
    const short* vtall = vt + (size_t)bh * HD * TT;

    const int sidx = wave * 64 + lane;
    const int srow = sidx >> 3;
    const int sseg = (sidx & 7) ^ (srow & 7);
    const short* kgsrc = kball + (size_t)srow * HD + sseg * 8;
    const short* vgsrc = vtall + (size_t)srow * TT + sseg * 8;

    bf16x8 qfh[2], qfl[2];
#pragma unroll
    for (int h = 0; h < 2; ++h) {
        qfh[h] = *(const bf16x8*)(qball + (size_t)(q_hi + l16) * HD + h * 32 + quad * 8);
        qfl[h] = *(const bf16x8*)(qball + (size_t)(q_lo + l16) * HD + h * 32 + quad * 8);
    }

    f32x4 o_hi[4] = {}, o_lo[4] = {};
    float ls_hi[4] = {0.f, 0.f, 0.f, 0.f}, ls_lo[4] = {0.f, 0.f, 0.f, 0.f};

    // prefetch subtile pair 0
#pragma unroll
    for (int s = 0; s < 2; ++s) {
        async_copy16(kgsrc + (size_t)s * 64 * HD, &Ksh[0][s][wave * 512]);
        async_copy16(vgsrc + s * 64, &Vsh[0][s][wave * 512]);
    }
    __syncthreads();

    for (int st = 0; st < nst; ++st) {
        const int buf = st & 1;
        if (st + 1 < nst) {
#pragma unroll
            for (int s = 0; s < 2; ++s) {
                int j64 = 2 * (st + 1) + s;
                async_copy16(kgsrc + (size_t)j64 * 64 * HD, &Ksh[buf ^ 1][s][wave * 512]);
                async_copy16(vgsrc + j64 * 64, &Vsh[buf ^ 1][s][wave * 512]);
            }
        }

#pragma unroll
        for (int s = 0; s < 2; ++s) {
            const int j0 = (2 * st + s) * 64;
            const short* Kt = Ksh[buf][s];
            const short* Vt = Vsh[buf][s];

            // ---------------- HI unit
            if (j0 <= q_hi + 15) {
                f32x4 sc[4];
#pragma unroll
                for (int cb = 0; cb < 4; ++cb) {
                    int row = cb * 16 + l16;
                    bf16x8 k0 = *(const bf16x8*)&Kt[(row * 8 + (quad ^ (row & 7))) * 8];
                    bf16x8 k1 = *(const bf16x8*)&Kt[(row * 8 + ((4 + quad) ^ (row & 7))) * 8];
                    f32x4 a = {};
                    a = __builtin_amdgcn_mfma_f32_16x16x32_bf16(qfh[0], k0, a, 0, 0, 0);
                    a = __builtin_amdgcn_mfma_f32_16x16x32_bf16(qfh[1], k1, a, 0, 0, 0);
                    sc[cb] = a;
                }
                if (j0 + 64 > q_hi) {
#pragma unroll
                    for (int cb = 0; cb < 4; ++cb) {
                        int j = j0 + cb * 16 + l16;
#pragma unroll
                        for (int r = 0; r < 4; ++r)
                            if (j > q_hi + quad * 4 + r) sc[cb][r] = -1e30f;
                    }
                }
#pragma unroll
                for (int cb = 0; cb < 4; ++cb)
#pragma unroll
                    for (int r = 0; r < 4; ++r) {
                        float p = fast_exp2(sc[cb][r]);
                        ls_hi[r] += p;
                        plds[wave][quad * 4 + r][cb * 16 + l16] = f32_to_bf16_bits(p);
                    }
                bf16x8 pa0 = *(const bf16x8*)&plds[wave][l16][quad * 8];
                bf16x8 pa1 = *(const bf16x8*)&plds[wave][l16][32 + quad * 8];
#pragma unroll
                for (int db = 0; db < 4; ++db) {
                    int row = db * 16 + l16;
                    bf16x8 v0 = *(const bf16x8*)&Vt[(row * 8 + (quad ^ (row & 7))) * 8];
                    bf16x8 v1 = *(const bf16x8*)&Vt[(row * 8 + ((4 + quad) ^ (row & 7))) * 8];
                    o_hi[db] = __builtin_amdgcn_mfma_f32_16x16x32_bf16(pa0, v0, o_hi[db], 0, 0, 0);
                    o_hi[db] = __builtin_amdgcn_mfma_f32_16x16x32_bf16(pa1, v1, o_hi[db], 0, 0, 0);
                }
            }

            // ---------------- LO unit
            if (j0 <= q_lo + 15) {
                f32x4 sc[4];
#pragma unroll
                for (int cb = 0; cb < 4; ++cb) {
                    int row = cb * 16 + l16;
                    bf16x8 k0 = *(const bf16x8*)&Kt[(row * 8 + (quad ^ (row & 7))) * 8];
                    bf16x8 k1 = *(const bf16x8*)&Kt[(row * 8 + ((4 + quad) ^ (row & 7))) * 8];
                    f32x4 a = {};
                    a = __builtin_amdgcn_mfma_f32_16x16x32_bf16(qfl[0], k0, a, 0, 0, 0);
                    a = __builtin_amdgcn_mfma_f32_16x16x32_bf16(qfl[1], k1, a, 0, 0, 0);
                    sc[cb] = a;
                }
                if (j0 + 64 > q_lo) {
#pragma unroll
                    for (int cb = 0; cb < 4; ++cb) {
                        int j = j0 + cb * 16 + l16;
#pragma unroll
                        for (int r = 0; r < 4; ++r)
                            if (j > q_lo + quad * 4 + r) sc[cb][r] = -1e30f;
                    }
                }
#pragma unroll
                for (int cb = 0; cb < 4; ++cb)
#pragma unroll
                    for (int r = 0; r < 4; ++r) {
                        float p = fast_exp2(sc[cb][r]);
                        ls_lo[r] += p;
                        plds[wave][quad * 4 + r][cb * 16 + l16] = f32_to_bf16_bits(p);
                    }
                bf16x8 pa0 = *(const bf16x8*)&plds[wave][l16][quad * 8];
                bf16x8 pa1 = *(const bf16x8*)&plds[wave][l16][32 + quad * 8];
#pragma unroll
                for (int db = 0; db < 4; ++db) {
                    int row = db * 16 + l16;
                    bf16x8 v0 = *(const bf16x8*)&Vt[(row * 8 + (quad ^ (row & 7))) * 8];
                    bf16x8 v1 = *(const bf16x8*)&Vt[(row * 8 + ((4 + quad) ^ (row & 7))) * 8];
                    o_lo[db] = __builtin_amdgcn_mfma_f32_16x16x32_bf16(pa0, v0, o_lo[db], 0, 0, 0);
                    o_lo[db] = __builtin_amdgcn_mfma_f32_16x16x32_bf16(pa1, v1, o_lo[db], 0, 0, 0);
                }
            }
        }
        __syncthreads();
    }

    const int b = bh >> 4, hd0 = (bh & 15) * HD;
    float inv_h[4], inv_l[4];
#pragma unroll
    for (int r = 0; r < 4; ++r) {
        float th = ls_hi[r], tl = ls_lo[r];
#pragma unroll
        for (int off = 1; off < 16; off <<= 1) {
            th += __shfl_xor(th, off, 64);
            tl += __shfl_xor(tl, off, 64);
        }
        inv_h[r] = 1.0f / th;
        inv_l[r] = 1.0f / tl;
    }
#pragma unroll
    for (int r = 0; r < 4; ++r) {
        int qh = q_hi + quad * 4 + r;
        int ql = q_lo + quad * 4 + r;
#pragma unroll
        for (int db = 0; db < 4; ++db) {
            ab[((size_t)(b * TT + qh)) * CC + hd0 + db * 16 + l16] =
                f32_to_bf16_bits(o_hi[db][r] * inv_h[r]);
            ab[((size_t)(b * TT + ql)) * CC + hd0 + db * 16 + l16] =
                f32_to_bf16_bits(o_lo[db][r] * inv_l[r]);
        }
    }
}

extern "C" void kernel_launch(void* const* d_in, const int* in_sizes, int n_in,
                              void* d_out, int out_size, void* d_ws, size_t ws_size,
                              hipStream_t stream) {
    const float* x      = (const float*)d_in[0];
    const float* w_attn = (const float*)d_in[1];
    const float* b_attn = (const float*)d_in[2];
    const float* w_proj = (const float*)d_in[3];
    const float* b_proj = (const float*)d_in[4];
    float* out = (float*)d_out;

    const size_t per = (size_t)BB * HH * TT * HD;  // 8,388,608
    short* xb      = (short*)d_ws;
    short* wt_attn = xb + per;
    short* wt_proj = wt_attn + (size_t)C3 * CC;
    short* qb      = wt_proj + (size_t)CC * CC;
    short* kb      = qb + per;
    short* vt      = kb + per;                     // [B,H,hd,T]
    short* ab      = vt + per;                     // [B,T,C] bf16

    cast_x<<<dim3(MM * CC / (256 * 8)), 256, 0, stream>>>(x, xb);
    tcast<<<dim3(C3 / 64, CC / 64), 256, 0, stream>>>(w_attn, wt_attn, CC, C3);
    tcast<<<dim3(CC / 64, CC / 64), 256, 0, stream>>>(w_proj, wt_proj, CC, CC);

    gemm128<true><<<dim3(C3 / 128, MM / 128), 256, 0, stream>>>(
        xb, wt_attn, b_attn, qb, kb, vt, nullptr, C3, CC);

    flash_attn<<<dim3(8, BB * HH), 512, 0, stream>>>(qb, kb, vt, ab);

    gemm128<false><<<dim3(CC / 128, MM / 128), 256, 0, stream>>>(
        ab, wt_proj, b_proj, nullptr, nullptr, nullptr, out, CC, CC);
}